// Round 1
// 542.643 us; speedup vs baseline: 1.1279x; 1.1279x over previous
//
#include <hip/hip_runtime.h>
#include <hip/hip_bf16.h>
#include <hip/hip_fp16.h>

#define N_NODES 100000
#define N_EDGES 20000
#define NNZ     1600000
#define D       128
#define STAR    64
#define NEG_SLOPE 0.2f

// edge counting-sort partition
#define NBLK_E  200         // chunks
#define CHUNK_E 8000        // NNZ / NBLK_E
#define BINS_E  10000       // bins per LDS pass (40 KB int), 2 passes

// multi-block scan: 256 threads x 16 elements
#define SCC 16
#define SC_PER_BLOCK (256 * SCC)   // 4096
#define SC_NBLK(n) (((n) + SC_PER_BLOCK - 1) / SC_PER_BLOCK)

// ---------------------------------------------------------------------------
// K1: fused node GEMM:  [X_init | X_feat] = X @ [Wx^T | Wv^T] + bias
// X_init -> fp32 d_out; X_feat -> fp16 ws table (gather payload).
// ---------------------------------------------------------------------------
#define BM 64
#define BN 64
#define BK 16

__global__ __launch_bounds__(256) void k_node_gemm(
    const float* __restrict__ X,
    const float* __restrict__ Wx, const float* __restrict__ Wxb,
    const float* __restrict__ Wv, const float* __restrict__ Wvb,
    float* __restrict__ Xinit, __half* __restrict__ Xf16)
{
    __shared__ float As[BK][BM + 4];
    __shared__ float Bs[BK][BN + 4];
    const int tid = threadIdx.x;
    const int bm = blockIdx.x * BM;
    const int bn = blockIdx.y * BN;        // 0,64,128,192
    const int lr = tid >> 2;
    const int lk = (tid & 3) * 4;
    const int tx = tid & 15, ty = tid >> 4;

    float acc[4][4] = {};

    for (int k0 = 0; k0 < D; k0 += BK) {
        float4 av = make_float4(0.f, 0.f, 0.f, 0.f);
        int node = bm + lr;
        if (node < N_NODES)
            av = *(const float4*)(X + (size_t)node * D + k0 + lk);
        As[lk + 0][lr] = av.x; As[lk + 1][lr] = av.y;
        As[lk + 2][lr] = av.z; As[lk + 3][lr] = av.w;
        int dd = bn + lr;
        const float* wsrc = (dd < D) ? (Wx + (size_t)dd * D)
                                     : (Wv + (size_t)(dd - D) * D);
        float4 bv = *(const float4*)(wsrc + k0 + lk);
        Bs[lk + 0][lr] = bv.x; Bs[lk + 1][lr] = bv.y;
        Bs[lk + 2][lr] = bv.z; Bs[lk + 3][lr] = bv.w;
        __syncthreads();
        #pragma unroll
        for (int kk = 0; kk < BK; ++kk) {
            float4 af = *(const float4*)&As[kk][ty * 4];
            float4 bf = *(const float4*)&Bs[kk][tx * 4];
            float a[4] = {af.x, af.y, af.z, af.w};
            float b[4] = {bf.x, bf.y, bf.z, bf.w};
            #pragma unroll
            for (int r = 0; r < 4; ++r)
                #pragma unroll
                for (int c = 0; c < 4; ++c)
                    acc[r][c] = fmaf(a[r], b[c], acc[r][c]);
        }
        __syncthreads();
    }

    const int gcol = bn + tx * 4;
    const bool isInit = (gcol < D);
    const int cc = isInit ? gcol : (gcol - D);
    const float* bias = isInit ? Wxb : Wvb;
    float4 bb = *(const float4*)(bias + cc);
    #pragma unroll
    for (int r = 0; r < 4; ++r) {
        int node = bm + ty * 4 + r;
        if (node < N_NODES) {
            float4 o = make_float4(acc[r][0] + bb.x, acc[r][1] + bb.y,
                                   acc[r][2] + bb.z, acc[r][3] + bb.w);
            if (isInit) {
                *(float4*)(Xinit + (size_t)node * D + cc) = o;
            } else {
                __half2 h01 = __floats2half2_rn(o.x, o.y);
                __half2 h23 = __floats2half2_rn(o.z, o.w);
                *(__half2*)(Xf16 + (size_t)node * D + cc) = h01;
                *(__half2*)(Xf16 + (size_t)node * D + cc + 2) = h23;
            }
        }
    }
}

// ---------------------------------------------------------------------------
// K2: wexp[n] = exp(leaky_relu(X_feat[n,:] . a_w)) — one wave per node.
// ---------------------------------------------------------------------------
__global__ __launch_bounds__(256) void k_score(
    const __half* __restrict__ Xf16, const float* __restrict__ aw,
    float* __restrict__ wexp)
{
    const int wave = threadIdx.x >> 6, lane = threadIdx.x & 63;
    const int node = blockIdx.x * 4 + wave;
    if (node >= N_NODES) return;
    __half2 h = *(const __half2*)(Xf16 + (size_t)node * D + lane * 2);
    float2 x = __half22float2(h);
    float2 a = *(const float2*)(aw + lane * 2);
    float s = x.x * a.x + x.y * a.y;
    #pragma unroll
    for (int off = 32; off > 0; off >>= 1) s += __shfl_down(s, off, 64);
    if (lane == 0) {
        float l = (s > 0.f) ? s : NEG_SLOPE * s;
        wexp[node] = expf(l);
    }
}

// ---------------------------------------------------------------------------
// K3: edge histogram + within-(block,bin) rank via LDS atomics ONLY.
// ---------------------------------------------------------------------------
__global__ __launch_bounds__(256) void k_part_e(
    const int* __restrict__ E, int* __restrict__ part,
    unsigned short* __restrict__ re)
{
    __shared__ int h[BINS_E];
    const int b = blockIdx.x;
    const int c0 = blockIdx.y * BINS_E;
    const int i0 = b * CHUNK_E;
    for (int t = threadIdx.x; t < BINS_E; t += 256) h[t] = 0;
    __syncthreads();
    for (int i = threadIdx.x; i < CHUNK_E; i += 256) {
        int c = E[i0 + i] - c0;
        if (c >= 0 && c < BINS_E) {
            int r = atomicAdd(&h[c], 1);            // LDS atomic, returns rank
            re[i0 + i] = (unsigned short)r;
        }
    }
    __syncthreads();
    for (int t = threadIdx.x; t < BINS_E; t += 256)
        part[(size_t)b * N_EDGES + c0 + t] = h[t];
}

// ---------------------------------------------------------------------------
// K4: node rank via ONE global atomic per incidence (returns rank).
// ---------------------------------------------------------------------------
__global__ __launch_bounds__(256) void k_rank_n(
    const int* __restrict__ V, int* __restrict__ nhist,
    unsigned short* __restrict__ rn)
{
    int i = blockIdx.x * 256 + threadIdx.x;
    if (i >= NNZ) return;
    int r = atomicAdd(nhist + V[i], 1);             // device atomic (rank)
    rn[i] = (unsigned short)r;
}

// ---------------------------------------------------------------------------
// K5: per-bin exclusive prefix over edge chunks; emits per-bin totals.
// ---------------------------------------------------------------------------
__global__ __launch_bounds__(256) void k_tot_e(
    int* __restrict__ part, int* __restrict__ tot)
{
    int bin = blockIdx.x * 256 + threadIdx.x;
    if (bin >= N_EDGES) return;
    int run = 0;
    for (int b = 0; b < NBLK_E; ++b) {
        size_t idx = (size_t)b * N_EDGES + bin;
        int v = part[idx];
        part[idx] = run;
        run += v;
    }
    tot[bin] = run;
}

// ---------------------------------------------------------------------------
// Multi-block scan, phase 1: per-block sums. 256 thr x 16 elems (int4).
// ---------------------------------------------------------------------------
__global__ __launch_bounds__(256) void k_scan_bsum(
    const int* __restrict__ cnt, int* __restrict__ bsum, int n)
{
    __shared__ int red[256];
    const int base = blockIdx.x * SC_PER_BLOCK + threadIdx.x * SCC;
    int s = 0;
    if (base + SCC <= n) {
        const int4* p4 = (const int4*)(cnt + base);
        #pragma unroll
        for (int j = 0; j < SCC / 4; ++j) {
            int4 v = p4[j];
            s += v.x + v.y + v.z + v.w;
        }
    } else {
        for (int i = base; i < n; ++i) s += cnt[i];
    }
    red[threadIdx.x] = s;
    __syncthreads();
    for (int d = 128; d > 0; d >>= 1) {
        if (threadIdx.x < d) red[threadIdx.x] += red[threadIdx.x + d];
        __syncthreads();
    }
    if (threadIdx.x == 0) bsum[blockIdx.x] = red[0];
}

// ---------------------------------------------------------------------------
// Phase 2: single small block turns bsum into exclusive block bases,
// writes total into off[n].  nb <= 1024.
// ---------------------------------------------------------------------------
__global__ __launch_bounds__(1024) void k_scan_bbase(
    int* __restrict__ bsum, int nb, int* __restrict__ off, int n)
{
    __shared__ int sums[1024];
    const int tid = threadIdx.x;
    sums[tid] = (tid < nb) ? bsum[tid] : 0;
    __syncthreads();
    for (int d = 1; d < 1024; d <<= 1) {
        int mine = sums[tid];
        int other = (tid >= d) ? sums[tid - d] : 0;
        __syncthreads();
        sums[tid] = mine + other;
        __syncthreads();
    }
    if (tid < nb) bsum[tid] = (tid > 0) ? sums[tid - 1] : 0;
    if (tid == 0) off[n] = sums[1023];
}

// ---------------------------------------------------------------------------
// Phase 3: per-block exclusive scan + block base -> off[i].
// ---------------------------------------------------------------------------
__global__ __launch_bounds__(256) void k_scan_out(
    const int* __restrict__ cnt, const int* __restrict__ bsum,
    int* __restrict__ off, int n)
{
    __shared__ int tsum[256];
    const int base = blockIdx.x * SC_PER_BLOCK + threadIdx.x * SCC;
    int vals[SCC];
    int s = 0;
    if (base + SCC <= n) {
        const int4* p4 = (const int4*)(cnt + base);
        #pragma unroll
        for (int j = 0; j < SCC / 4; ++j) {
            int4 v = p4[j];
            vals[4 * j + 0] = v.x; vals[4 * j + 1] = v.y;
            vals[4 * j + 2] = v.z; vals[4 * j + 3] = v.w;
            s += v.x + v.y + v.z + v.w;
        }
    } else {
        #pragma unroll
        for (int j = 0; j < SCC; ++j) {
            int i = base + j;
            vals[j] = (i < n) ? cnt[i] : 0;
            s += vals[j];
        }
    }
    tsum[threadIdx.x] = s;
    __syncthreads();
    for (int d = 1; d < 256; d <<= 1) {
        int mine = tsum[threadIdx.x];
        int other = (threadIdx.x >= d) ? tsum[threadIdx.x - d] : 0;
        __syncthreads();
        tsum[threadIdx.x] = mine + other;
        __syncthreads();
    }
    int run = bsum[blockIdx.x] + ((threadIdx.x > 0) ? tsum[threadIdx.x - 1] : 0);
    #pragma unroll
    for (int j = 0; j < SCC; ++j) {
        int i = base + j;
        if (i < n) { off[i] = run; run += vals[j]; }
    }
}

// ---------------------------------------------------------------------------
// K6: edge scatter, NO atomics. w gathered from 400 KB wexp table.
// ---------------------------------------------------------------------------
__global__ __launch_bounds__(256) void k_scatter_e(
    const int* __restrict__ V, const int* __restrict__ E,
    const float* __restrict__ wexp, const unsigned short* __restrict__ re,
    const int* __restrict__ eoff, const int* __restrict__ part,
    int2* __restrict__ epairs)
{
    __shared__ int base[BINS_E];
    const int b = blockIdx.x;
    const int c0 = blockIdx.y * BINS_E;
    const int i0 = b * CHUNK_E;
    for (int t = threadIdx.x; t < BINS_E; t += 256)
        base[t] = part[(size_t)b * N_EDGES + c0 + t] + eoff[c0 + t];
    __syncthreads();
    for (int i = threadIdx.x; i < CHUNK_E; i += 256) {
        int e = E[i0 + i];
        int c = e - c0;
        if (c >= 0 && c < BINS_E) {
            int v = V[i0 + i];
            float w = wexp[v];
            epairs[base[c] + re[i0 + i]] = make_int2(v, __float_as_int(w));
        }
    }
}

// ---------------------------------------------------------------------------
// K7: node scatter, NO atomics, flat grid: pos = noff[V[i]] + rn[i].
// ---------------------------------------------------------------------------
__global__ __launch_bounds__(256) void k_scatter_n(
    const int* __restrict__ V, const int* __restrict__ E,
    const unsigned short* __restrict__ rn, const int* __restrict__ noff,
    int* __restrict__ nedges)
{
    int i = blockIdx.x * 256 + threadIdx.x;
    if (i >= NNZ) return;
    nedges[noff[V[i]] + rn[i]] = E[i];
}

// ---------------------------------------------------------------------------
// helper: accumulate 4 dims (stored as 4 halves in a float2) with weight w
// ---------------------------------------------------------------------------
__device__ __forceinline__ void acc4h(float w, float2 raw,
                                      float& a0, float& a1,
                                      float& a2, float& a3)
{
    __half2 h01 = *(__half2*)&raw.x;
    __half2 h23 = *(__half2*)&raw.y;
    float2 f01 = __half22float2(h01);
    float2 f23 = __half22float2(h23);
    a0 = fmaf(w, f01.x, a0); a1 = fmaf(w, f01.y, a1);
    a2 = fmaf(w, f23.x, a2); a3 = fmaf(w, f23.y, a3);
}

// ---------------------------------------------------------------------------
// K8: per-edge aggregation. ONE WAVE PER EDGE, TWO 32-LANE SLOTS.
// Slot s (lanes 32s..32s+31) handles incidence j+s; each lane loads 8 B
// (4 dims as half4) so ONE wave load instruction fetches TWO rows.
// Slot partials combined with one __shfl_xor(...,32) at the end.
// ---------------------------------------------------------------------------
__global__ __launch_bounds__(256) void k_edge_agg(
    const int2* __restrict__ epairs, const int* __restrict__ eoff,
    const __half* __restrict__ Xf16, const float* __restrict__ S,
    float* __restrict__ emsg)
{
    const int wave = threadIdx.x >> 6, lane = threadIdx.x & 63;
    const int e = blockIdx.x * 4 + wave;
    if (e >= N_EDGES) return;
    const int beg = eoff[e], end = eoff[e + 1];
    const int slot = lane >> 5;          // 0 or 1
    const int sl = lane & 31;            // lane within slot: dims 4*sl..4*sl+3
    float a0 = 0.f, a1 = 0.f, a2 = 0.f, a3 = 0.f, dsum = 0.f;
    int j = beg;
    // main: 4 incidences per iteration; 2 independent row-pair gathers
    #pragma unroll 2
    for (; j + 3 < end; j += 4) {
        int2 pA = epairs[j + slot];
        int2 pB = epairs[j + 2 + slot];
        float wA = __int_as_float(pA.y), wB = __int_as_float(pB.y);
        float2 rA = *(const float2*)(Xf16 + (size_t)pA.x * D + sl * 4);
        float2 rB = *(const float2*)(Xf16 + (size_t)pB.x * D + sl * 4);
        dsum += wA + wB;
        acc4h(wA, rA, a0, a1, a2, a3);
        acc4h(wB, rB, a0, a1, a2, a3);
    }
    // pair tail
    for (; j + 1 < end; j += 2) {
        int2 p = epairs[j + slot];
        float w = __int_as_float(p.y);
        float2 r = *(const float2*)(Xf16 + (size_t)p.x * D + sl * 4);
        dsum += w;
        acc4h(w, r, a0, a1, a2, a3);
    }
    // single tail: only slot 0
    if (j < end && slot == 0) {
        int2 p = epairs[j];
        float w = __int_as_float(p.y);
        float2 r = *(const float2*)(Xf16 + (size_t)p.x * D + sl * 4);
        dsum += w;
        acc4h(w, r, a0, a1, a2, a3);
    }
    // combine the two slots: lane l and l^32 hold the same 4 dims
    a0 += __shfl_xor(a0, 32, 64);
    a1 += __shfl_xor(a1, 32, 64);
    a2 += __shfl_xor(a2, 32, 64);
    a3 += __shfl_xor(a3, 32, 64);
    dsum += __shfl_xor(dsum, 32, 64);

    float inv = (end > beg) ? 1.f / dsum : 0.f;
    float y0 = a0 * inv, y1 = a1 * inv, y2 = a2 * inv, y3 = a3 * inv;
    y0 = (y0 > 0.f) ? y0 : expm1f(y0);
    y1 = (y1 > 0.f) ? y1 : expm1f(y1);
    y2 = (y2 > 0.f) ? y2 : expm1f(y2);
    y3 = (y3 > 0.f) ? y3 : expm1f(y3);
    const size_t rb = (size_t)e * (D + STAR);
    if (slot == 0) {
        *(float4*)(emsg + rb + sl * 4) = make_float4(y0, y1, y2, y3);
    } else {
        float2 s2 = *(const float2*)(S + (size_t)e * STAR + sl * 2);
        *(float2*)(emsg + rb + D + sl * 2) = s2;
    }
}

// ---------------------------------------------------------------------------
// K9: edge GEMM: Y = e_msg @ Wt^T + Wt_b -> fp16 (gather payload).
// M=20000, N=128, K=192.
// ---------------------------------------------------------------------------
__global__ __launch_bounds__(256) void k_edge_gemm(
    const float* __restrict__ A, const float* __restrict__ Wt,
    const float* __restrict__ Wtb, __half* __restrict__ Y16)
{
    __shared__ float As[BK][BM + 4];
    __shared__ float Bs[BK][BN + 4];
    const int KDIM = D + STAR;   // 192
    const int tid = threadIdx.x;
    const int bm = blockIdx.x * BM;
    const int bn = blockIdx.y * BN;        // 0,64
    const int lr = tid >> 2;
    const int lk = (tid & 3) * 4;
    const int tx = tid & 15, ty = tid >> 4;

    float acc[4][4] = {};

    for (int k0 = 0; k0 < KDIM; k0 += BK) {
        float4 av = make_float4(0.f, 0.f, 0.f, 0.f);
        int row = bm + lr;
        if (row < N_EDGES)
            av = *(const float4*)(A + (size_t)row * KDIM + k0 + lk);
        As[lk + 0][lr] = av.x; As[lk + 1][lr] = av.y;
        As[lk + 2][lr] = av.z; As[lk + 3][lr] = av.w;
        int dd = bn + lr;   // < 128 always
        float4 bv = *(const float4*)(Wt + (size_t)dd * KDIM + k0 + lk);
        Bs[lk + 0][lr] = bv.x; Bs[lk + 1][lr] = bv.y;
        Bs[lk + 2][lr] = bv.z; Bs[lk + 3][lr] = bv.w;
        __syncthreads();
        #pragma unroll
        for (int kk = 0; kk < BK; ++kk) {
            float4 af = *(const float4*)&As[kk][ty * 4];
            float4 bf = *(const float4*)&Bs[kk][tx * 4];
            float a[4] = {af.x, af.y, af.z, af.w};
            float b[4] = {bf.x, bf.y, bf.z, bf.w};
            #pragma unroll
            for (int r = 0; r < 4; ++r)
                #pragma unroll
                for (int c = 0; c < 4; ++c)
                    acc[r][c] = fmaf(a[r], b[c], acc[r][c]);
        }
        __syncthreads();
    }

    const int gcol = bn + tx * 4;
    float4 bb = *(const float4*)(Wtb + gcol);
    #pragma unroll
    for (int r = 0; r < 4; ++r) {
        int row = bm + ty * 4 + r;
        if (row < N_EDGES) {
            __half2 h01 = __floats2half2_rn(acc[r][0] + bb.x, acc[r][1] + bb.y);
            __half2 h23 = __floats2half2_rn(acc[r][2] + bb.z, acc[r][3] + bb.w);
            *(__half2*)(Y16 + (size_t)row * D + gcol) = h01;
            *(__half2*)(Y16 + (size_t)row * D + gcol + 2) = h23;
        }
    }
}

// ---------------------------------------------------------------------------
// K10: per-node aggregation. ONE WAVE PER NODE, TWO 32-LANE SLOTS (as K8).
// out[v] = elu(mean_j Y[e_j]) + out[v]   (out holds X_init).
// ---------------------------------------------------------------------------
__global__ __launch_bounds__(256) void k_node_agg(
    const int* __restrict__ nedges, const int* __restrict__ noff,
    const __half* __restrict__ Y16, float* __restrict__ out)
{
    const int wave = threadIdx.x >> 6, lane = threadIdx.x & 63;
    const int v = blockIdx.x * 4 + wave;
    if (v >= N_NODES) return;
    const int beg = noff[v], end = noff[v + 1];
    const int slot = lane >> 5;
    const int sl = lane & 31;
    float a0 = 0.f, a1 = 0.f, a2 = 0.f, a3 = 0.f;
    int j = beg;
    #pragma unroll 2
    for (; j + 3 < end; j += 4) {
        int eA = nedges[j + slot];
        int eB = nedges[j + 2 + slot];
        float2 rA = *(const float2*)(Y16 + (size_t)eA * D + sl * 4);
        float2 rB = *(const float2*)(Y16 + (size_t)eB * D + sl * 4);
        acc4h(1.f, rA, a0, a1, a2, a3);
        acc4h(1.f, rB, a0, a1, a2, a3);
    }
    for (; j + 1 < end; j += 2) {
        int eA = nedges[j + slot];
        float2 rA = *(const float2*)(Y16 + (size_t)eA * D + sl * 4);
        acc4h(1.f, rA, a0, a1, a2, a3);
    }
    if (j < end && slot == 0) {
        int eA = nedges[j];
        float2 rA = *(const float2*)(Y16 + (size_t)eA * D + sl * 4);
        acc4h(1.f, rA, a0, a1, a2, a3);
    }
    a0 += __shfl_xor(a0, 32, 64);
    a1 += __shfl_xor(a1, 32, 64);
    a2 += __shfl_xor(a2, 32, 64);
    a3 += __shfl_xor(a3, 32, 64);

    int cnt = end - beg;
    float invc = 1.f / (float)max(cnt, 1);
    float x0 = a0 * invc, x1 = a1 * invc, x2 = a2 * invc, x3 = a3 * invc;
    x0 = (x0 > 0.f) ? x0 : expm1f(x0);
    x1 = (x1 > 0.f) ? x1 : expm1f(x1);
    x2 = (x2 > 0.f) ? x2 : expm1f(x2);
    x3 = (x3 > 0.f) ? x3 : expm1f(x3);
    if (slot == 0) {
        float4* o = (float4*)(out + (size_t)v * D + sl * 4);
        float4 cur = *o;
        *o = make_float4(cur.x + x0, cur.y + x1, cur.z + x2, cur.w + x3);
    }
}

// ---------------------------------------------------------------------------
extern "C" void kernel_launch(void* const* d_in, const int* in_sizes, int n_in,
                              void* d_out, int out_size, void* d_ws, size_t ws_size,
                              hipStream_t stream)
{
    const float* X    = (const float*)d_in[0];
    const int*   V    = (const int*)  d_in[1];
    const int*   E    = (const int*)  d_in[2];
    const float* S    = (const float*)d_in[3];
    const float* Wx_w = (const float*)d_in[4];
    const float* Wx_b = (const float*)d_in[5];
    const float* Wv_w = (const float*)d_in[6];
    const float* Wv_b = (const float*)d_in[7];
    const float* a_w  = (const float*)d_in[8];
    const float* Wt_w = (const float*)d_in[9];
    const float* Wt_b = (const float*)d_in[10];
    float* out = (float*)d_out;

    char* p = (char*)d_ws;
    auto take = [&](size_t bytes) -> char* {
        char* r = p;
        p += (bytes + 255) & ~(size_t)255;
        return r;
    };

    __half* Xf16  = (__half*)take((size_t)N_NODES * D * 2);
    float*  wexp  = (float*) take((size_t)N_NODES * 4);
    int*    part_e = (int*)  take((size_t)NBLK_E * N_EDGES * 4);
    int*    tot_e = (int*)   take((size_t)N_EDGES * 4);
    int*    nhist = (int*)   take((size_t)N_NODES * 4);
    int*    eoff  = (int*)   take((size_t)(N_EDGES + 1) * 4);
    int*    noff  = (int*)   take((size_t)(N_NODES + 1) * 4);
    int*    bsum_e = (int*)  take((size_t)SC_NBLK(N_EDGES) * 4);
    int*    bsum_n = (int*)  take((size_t)SC_NBLK(N_NODES) * 4);
    unsigned short* re = (unsigned short*)take((size_t)NNZ * 2);
    unsigned short* rn = (unsigned short*)take((size_t)NNZ * 2);
    int2*   epairs = (int2*) take((size_t)NNZ * 8);
    int*    nedges = (int*)  take((size_t)NNZ * 4);
    float*  emsg  = (float*) take((size_t)N_EDGES * (D + STAR) * 4);
    __half* Y16   = (__half*)take((size_t)N_EDGES * D * 2);

    hipMemsetAsync(nhist, 0, (size_t)N_NODES * 4, stream);

    dim3 g1((N_NODES + BM - 1) / BM, 4);
    k_node_gemm<<<g1, 256, 0, stream>>>(X, Wx_w, Wx_b, Wv_w, Wv_b, out, Xf16);

    k_score<<<(N_NODES + 3) / 4, 256, 0, stream>>>(Xf16, a_w, wexp);

    k_part_e<<<dim3(NBLK_E, 2), 256, 0, stream>>>(E, part_e, re);

    k_rank_n<<<(NNZ + 255) / 256, 256, 0, stream>>>(V, nhist, rn);

    k_tot_e<<<(N_EDGES + 255) / 256, 256, 0, stream>>>(part_e, tot_e);

    // edge scan (n = 20000, 5 blocks)
    k_scan_bsum<<<SC_NBLK(N_EDGES), 256, 0, stream>>>(tot_e, bsum_e, N_EDGES);
    k_scan_bbase<<<1, 1024, 0, stream>>>(bsum_e, SC_NBLK(N_EDGES), eoff, N_EDGES);
    k_scan_out<<<SC_NBLK(N_EDGES), 256, 0, stream>>>(tot_e, bsum_e, eoff, N_EDGES);

    // node scan (n = 100000, 25 blocks)
    k_scan_bsum<<<SC_NBLK(N_NODES), 256, 0, stream>>>(nhist, bsum_n, N_NODES);
    k_scan_bbase<<<1, 1024, 0, stream>>>(bsum_n, SC_NBLK(N_NODES), noff, N_NODES);
    k_scan_out<<<SC_NBLK(N_NODES), 256, 0, stream>>>(nhist, bsum_n, noff, N_NODES);

    k_scatter_e<<<dim3(NBLK_E, 2), 256, 0, stream>>>(V, E, wexp, re, eoff,
                                                     part_e, epairs);
    k_scatter_n<<<(NNZ + 255) / 256, 256, 0, stream>>>(V, E, rn, noff, nedges);

    k_edge_agg<<<(N_EDGES + 3) / 4, 256, 0, stream>>>(epairs, eoff, Xf16, S, emsg);

    dim3 g6((N_EDGES + BM - 1) / BM, 2);
    k_edge_gemm<<<g6, 256, 0, stream>>>(emsg, Wt_w, Wt_b, Y16);

    k_node_agg<<<(N_NODES + 3) / 4, 256, 0, stream>>>(nedges, noff, Y16, out);
}

// Round 2
// 526.713 us; speedup vs baseline: 1.1620x; 1.0302x over previous
//
#include <hip/hip_runtime.h>
#include <hip/hip_bf16.h>
#include <hip/hip_fp16.h>

#define N_NODES 100000
#define N_EDGES 20000
#define NNZ     1600000
#define D       128
#define STAR    64
#define NEG_SLOPE 0.2f

// edge counting-sort partition
#define NBLK_E  200         // chunks
#define CHUNK_E 8000        // NNZ / NBLK_E
#define BINS_E  10000       // bins per LDS pass (40 KB int), 2 passes

// multi-block scan: 256 threads x 16 elements
#define SCC 16
#define SC_PER_BLOCK (256 * SCC)   // 4096
#define SC_NBLK(n) (((n) + SC_PER_BLOCK - 1) / SC_PER_BLOCK)

typedef _Float16 half8 __attribute__((ext_vector_type(8)));
typedef float    floatx4 __attribute__((ext_vector_type(4)));

// pack 8 fp32 (two float4) -> half8 fragment
__device__ __forceinline__ half8 cvt8(float4 f0, float4 f1)
{
    half8 h;
    h[0] = (_Float16)f0.x; h[1] = (_Float16)f0.y;
    h[2] = (_Float16)f0.z; h[3] = (_Float16)f0.w;
    h[4] = (_Float16)f1.x; h[5] = (_Float16)f1.y;
    h[6] = (_Float16)f1.z; h[7] = (_Float16)f1.w;
    return h;
}

// ---------------------------------------------------------------------------
// K1: fused node GEMM on MATRIX CORES (fp16 in, fp32 acc), NO LDS.
//   [X_init | X_feat] = X @ [Wx^T | Wv^T] + bias
// Block = 64 rows x 256 cols, 4 waves; wave w owns 64x64 tile (cols 64w..).
// Waves 0,1 -> X_init (fp32 out); waves 2,3 -> X_feat (fp16 table).
// A-frags gathered from global (L1-serviced, 4x wave reuse); B-frags from
// L2-resident 131 KB weight matrix. fp32->fp16 cvt in regs. Zero barriers.
// mfma_f32_16x16x32_f16 layouts: A row=lane&15, k=(lane>>4)*8+e (contig);
// B col=lane&15, same k; C/D col=lane&15, row=(lane>>4)*4+reg.
// ---------------------------------------------------------------------------
__global__ __launch_bounds__(256) void k_node_gemm(
    const float* __restrict__ X,
    const float* __restrict__ Wx, const float* __restrict__ Wxb,
    const float* __restrict__ Wv, const float* __restrict__ Wvb,
    float* __restrict__ Xinit, __half* __restrict__ Xf16)
{
    const int w    = threadIdx.x >> 6;
    const int lane = threadIdx.x & 63;
    const int bm   = blockIdx.x * 64;
    const int colbase = w * 64;                 // combined col 0..255
    const bool isInit = (colbase < D);
    const float* Wsrc = isInit ? Wx : Wv;
    const float* bias = isInit ? Wxb : Wvb;
    const int lc = colbase & (D - 1);           // 0 or 64 within W

    const int r16 = lane & 15;
    const int g8  = (lane >> 4) * 8;

    floatx4 acc[4][4] = {};

    #pragma unroll
    for (int ks = 0; ks < 4; ++ks) {
        const int k0 = ks * 32 + g8;
        half8 b[4], a[4];
        #pragma unroll
        for (int n = 0; n < 4; ++n) {
            const float* src = Wsrc + (size_t)(lc + n * 16 + r16) * D + k0;
            float4 f0 = *(const float4*)(src);
            float4 f1 = *(const float4*)(src + 4);
            b[n] = cvt8(f0, f1);
        }
        #pragma unroll
        for (int m = 0; m < 4; ++m) {
            int row = bm + m * 16 + r16;
            if (row >= N_NODES) row = N_NODES - 1;   // stores guarded below
            const float* src = X + (size_t)row * D + k0;
            float4 f0 = *(const float4*)(src);
            float4 f1 = *(const float4*)(src + 4);
            a[m] = cvt8(f0, f1);
        }
        #pragma unroll
        for (int m = 0; m < 4; ++m)
            #pragma unroll
            for (int n = 0; n < 4; ++n)
                acc[m][n] = __builtin_amdgcn_mfma_f32_16x16x32_f16(
                    a[m], b[n], acc[m][n], 0, 0, 0);
    }

    const int rq = (lane >> 4) * 4;
    #pragma unroll
    for (int n = 0; n < 4; ++n) {
        const int c = colbase + n * 16 + r16;    // combined col
        const float bv = bias[c & (D - 1)];
        #pragma unroll
        for (int m = 0; m < 4; ++m) {
            #pragma unroll
            for (int q = 0; q < 4; ++q) {
                const int row = bm + m * 16 + rq + q;
                if (row < N_NODES) {
                    float val = acc[m][n][q] + bv;
                    if (isInit)
                        Xinit[(size_t)row * D + c] = val;
                    else
                        Xf16[(size_t)row * D + (c - D)] = __float2half(val);
                }
            }
        }
    }
}

// ---------------------------------------------------------------------------
// K2: wexp[n] = exp(leaky_relu(X_feat[n,:] . a_w)) — one wave per node.
// ---------------------------------------------------------------------------
__global__ __launch_bounds__(256) void k_score(
    const __half* __restrict__ Xf16, const float* __restrict__ aw,
    float* __restrict__ wexp)
{
    const int wave = threadIdx.x >> 6, lane = threadIdx.x & 63;
    const int node = blockIdx.x * 4 + wave;
    if (node >= N_NODES) return;
    __half2 h = *(const __half2*)(Xf16 + (size_t)node * D + lane * 2);
    float2 x = __half22float2(h);
    float2 a = *(const float2*)(aw + lane * 2);
    float s = x.x * a.x + x.y * a.y;
    #pragma unroll
    for (int off = 32; off > 0; off >>= 1) s += __shfl_down(s, off, 64);
    if (lane == 0) {
        float l = (s > 0.f) ? s : NEG_SLOPE * s;
        wexp[node] = expf(l);
    }
}

// ---------------------------------------------------------------------------
// K3: edge histogram + within-(block,bin) rank via LDS atomics ONLY.
// ---------------------------------------------------------------------------
__global__ __launch_bounds__(256) void k_part_e(
    const int* __restrict__ E, int* __restrict__ part,
    unsigned short* __restrict__ re)
{
    __shared__ int h[BINS_E];
    const int b = blockIdx.x;
    const int c0 = blockIdx.y * BINS_E;
    const int i0 = b * CHUNK_E;
    for (int t = threadIdx.x; t < BINS_E; t += 256) h[t] = 0;
    __syncthreads();
    for (int i = threadIdx.x; i < CHUNK_E; i += 256) {
        int c = E[i0 + i] - c0;
        if (c >= 0 && c < BINS_E) {
            int r = atomicAdd(&h[c], 1);            // LDS atomic, returns rank
            re[i0 + i] = (unsigned short)r;
        }
    }
    __syncthreads();
    for (int t = threadIdx.x; t < BINS_E; t += 256)
        part[(size_t)b * N_EDGES + c0 + t] = h[t];
}

// ---------------------------------------------------------------------------
// K4: node rank via ONE global atomic per incidence (returns rank).
// ---------------------------------------------------------------------------
__global__ __launch_bounds__(256) void k_rank_n(
    const int* __restrict__ V, int* __restrict__ nhist,
    unsigned short* __restrict__ rn)
{
    int i = blockIdx.x * 256 + threadIdx.x;
    if (i >= NNZ) return;
    int r = atomicAdd(nhist + V[i], 1);             // device atomic (rank)
    rn[i] = (unsigned short)r;
}

// ---------------------------------------------------------------------------
// K5: per-bin exclusive prefix over edge chunks; emits per-bin totals.
// ---------------------------------------------------------------------------
__global__ __launch_bounds__(256) void k_tot_e(
    int* __restrict__ part, int* __restrict__ tot)
{
    int bin = blockIdx.x * 256 + threadIdx.x;
    if (bin >= N_EDGES) return;
    int run = 0;
    for (int b = 0; b < NBLK_E; ++b) {
        size_t idx = (size_t)b * N_EDGES + bin;
        int v = part[idx];
        part[idx] = run;
        run += v;
    }
    tot[bin] = run;
}

// ---------------------------------------------------------------------------
// Multi-block scan, phase 1: per-block sums. 256 thr x 16 elems (int4).
// ---------------------------------------------------------------------------
__global__ __launch_bounds__(256) void k_scan_bsum(
    const int* __restrict__ cnt, int* __restrict__ bsum, int n)
{
    __shared__ int red[256];
    const int base = blockIdx.x * SC_PER_BLOCK + threadIdx.x * SCC;
    int s = 0;
    if (base + SCC <= n) {
        const int4* p4 = (const int4*)(cnt + base);
        #pragma unroll
        for (int j = 0; j < SCC / 4; ++j) {
            int4 v = p4[j];
            s += v.x + v.y + v.z + v.w;
        }
    } else {
        for (int i = base; i < n; ++i) s += cnt[i];
    }
    red[threadIdx.x] = s;
    __syncthreads();
    for (int d = 128; d > 0; d >>= 1) {
        if (threadIdx.x < d) red[threadIdx.x] += red[threadIdx.x + d];
        __syncthreads();
    }
    if (threadIdx.x == 0) bsum[blockIdx.x] = red[0];
}

// ---------------------------------------------------------------------------
// Phase 2: single small block turns bsum into exclusive block bases,
// writes total into off[n].  nb <= 1024.
// ---------------------------------------------------------------------------
__global__ __launch_bounds__(1024) void k_scan_bbase(
    int* __restrict__ bsum, int nb, int* __restrict__ off, int n)
{
    __shared__ int sums[1024];
    const int tid = threadIdx.x;
    sums[tid] = (tid < nb) ? bsum[tid] : 0;
    __syncthreads();
    for (int d = 1; d < 1024; d <<= 1) {
        int mine = sums[tid];
        int other = (tid >= d) ? sums[tid - d] : 0;
        __syncthreads();
        sums[tid] = mine + other;
        __syncthreads();
    }
    if (tid < nb) bsum[tid] = (tid > 0) ? sums[tid - 1] : 0;
    if (tid == 0) off[n] = sums[1023];
}

// ---------------------------------------------------------------------------
// Phase 3: per-block exclusive scan + block base -> off[i].
// ---------------------------------------------------------------------------
__global__ __launch_bounds__(256) void k_scan_out(
    const int* __restrict__ cnt, const int* __restrict__ bsum,
    int* __restrict__ off, int n)
{
    __shared__ int tsum[256];
    const int base = blockIdx.x * SC_PER_BLOCK + threadIdx.x * SCC;
    int vals[SCC];
    int s = 0;
    if (base + SCC <= n) {
        const int4* p4 = (const int4*)(cnt + base);
        #pragma unroll
        for (int j = 0; j < SCC / 4; ++j) {
            int4 v = p4[j];
            vals[4 * j + 0] = v.x; vals[4 * j + 1] = v.y;
            vals[4 * j + 2] = v.z; vals[4 * j + 3] = v.w;
            s += v.x + v.y + v.z + v.w;
        }
    } else {
        #pragma unroll
        for (int j = 0; j < SCC; ++j) {
            int i = base + j;
            vals[j] = (i < n) ? cnt[i] : 0;
            s += vals[j];
        }
    }
    tsum[threadIdx.x] = s;
    __syncthreads();
    for (int d = 1; d < 256; d <<= 1) {
        int mine = tsum[threadIdx.x];
        int other = (threadIdx.x >= d) ? tsum[threadIdx.x - d] : 0;
        __syncthreads();
        tsum[threadIdx.x] = mine + other;
        __syncthreads();
    }
    int run = bsum[blockIdx.x] + ((threadIdx.x > 0) ? tsum[threadIdx.x - 1] : 0);
    #pragma unroll
    for (int j = 0; j < SCC; ++j) {
        int i = base + j;
        if (i < n) { off[i] = run; run += vals[j]; }
    }
}

// ---------------------------------------------------------------------------
// K6: edge scatter, NO atomics. w gathered from 400 KB wexp table.
// ---------------------------------------------------------------------------
__global__ __launch_bounds__(256) void k_scatter_e(
    const int* __restrict__ V, const int* __restrict__ E,
    const float* __restrict__ wexp, const unsigned short* __restrict__ re,
    const int* __restrict__ eoff, const int* __restrict__ part,
    int2* __restrict__ epairs)
{
    __shared__ int base[BINS_E];
    const int b = blockIdx.x;
    const int c0 = blockIdx.y * BINS_E;
    const int i0 = b * CHUNK_E;
    for (int t = threadIdx.x; t < BINS_E; t += 256)
        base[t] = part[(size_t)b * N_EDGES + c0 + t] + eoff[c0 + t];
    __syncthreads();
    for (int i = threadIdx.x; i < CHUNK_E; i += 256) {
        int e = E[i0 + i];
        int c = e - c0;
        if (c >= 0 && c < BINS_E) {
            int v = V[i0 + i];
            float w = wexp[v];
            epairs[base[c] + re[i0 + i]] = make_int2(v, __float_as_int(w));
        }
    }
}

// ---------------------------------------------------------------------------
// K7: node scatter, NO atomics, flat grid: pos = noff[V[i]] + rn[i].
// ---------------------------------------------------------------------------
__global__ __launch_bounds__(256) void k_scatter_n(
    const int* __restrict__ V, const int* __restrict__ E,
    const unsigned short* __restrict__ rn, const int* __restrict__ noff,
    int* __restrict__ nedges)
{
    int i = blockIdx.x * 256 + threadIdx.x;
    if (i >= NNZ) return;
    nedges[noff[V[i]] + rn[i]] = E[i];
}

// ---------------------------------------------------------------------------
// helper: accumulate 4 dims (stored as 4 halves in a float2) with weight w
// ---------------------------------------------------------------------------
__device__ __forceinline__ void acc4h(float w, float2 raw,
                                      float& a0, float& a1,
                                      float& a2, float& a3)
{
    __half2 h01 = *(__half2*)&raw.x;
    __half2 h23 = *(__half2*)&raw.y;
    float2 f01 = __half22float2(h01);
    float2 f23 = __half22float2(h23);
    a0 = fmaf(w, f01.x, a0); a1 = fmaf(w, f01.y, a1);
    a2 = fmaf(w, f23.x, a2); a3 = fmaf(w, f23.y, a3);
}

// ---------------------------------------------------------------------------
// K8: per-edge aggregation. ONE WAVE PER EDGE, TWO 32-LANE SLOTS.
// Slot s (lanes 32s..32s+31) handles incidence j+s; each lane loads 8 B
// (4 dims as half4) so ONE wave load instruction fetches TWO rows.
// Slot partials combined with one __shfl_xor(...,32) at the end.
// ---------------------------------------------------------------------------
__global__ __launch_bounds__(256) void k_edge_agg(
    const int2* __restrict__ epairs, const int* __restrict__ eoff,
    const __half* __restrict__ Xf16, const float* __restrict__ S,
    float* __restrict__ emsg)
{
    const int wave = threadIdx.x >> 6, lane = threadIdx.x & 63;
    const int e = blockIdx.x * 4 + wave;
    if (e >= N_EDGES) return;
    const int beg = eoff[e], end = eoff[e + 1];
    const int slot = lane >> 5;          // 0 or 1
    const int sl = lane & 31;            // lane within slot: dims 4*sl..4*sl+3
    float a0 = 0.f, a1 = 0.f, a2 = 0.f, a3 = 0.f, dsum = 0.f;
    int j = beg;
    // main: 4 incidences per iteration; 2 independent row-pair gathers
    #pragma unroll 2
    for (; j + 3 < end; j += 4) {
        int2 pA = epairs[j + slot];
        int2 pB = epairs[j + 2 + slot];
        float wA = __int_as_float(pA.y), wB = __int_as_float(pB.y);
        float2 rA = *(const float2*)(Xf16 + (size_t)pA.x * D + sl * 4);
        float2 rB = *(const float2*)(Xf16 + (size_t)pB.x * D + sl * 4);
        dsum += wA + wB;
        acc4h(wA, rA, a0, a1, a2, a3);
        acc4h(wB, rB, a0, a1, a2, a3);
    }
    // pair tail
    for (; j + 1 < end; j += 2) {
        int2 p = epairs[j + slot];
        float w = __int_as_float(p.y);
        float2 r = *(const float2*)(Xf16 + (size_t)p.x * D + sl * 4);
        dsum += w;
        acc4h(w, r, a0, a1, a2, a3);
    }
    // single tail: only slot 0
    if (j < end && slot == 0) {
        int2 p = epairs[j];
        float w = __int_as_float(p.y);
        float2 r = *(const float2*)(Xf16 + (size_t)p.x * D + sl * 4);
        dsum += w;
        acc4h(w, r, a0, a1, a2, a3);
    }
    // combine the two slots: lane l and l^32 hold the same 4 dims
    a0 += __shfl_xor(a0, 32, 64);
    a1 += __shfl_xor(a1, 32, 64);
    a2 += __shfl_xor(a2, 32, 64);
    a3 += __shfl_xor(a3, 32, 64);
    dsum += __shfl_xor(dsum, 32, 64);

    float inv = (end > beg) ? 1.f / dsum : 0.f;
    float y0 = a0 * inv, y1 = a1 * inv, y2 = a2 * inv, y3 = a3 * inv;
    y0 = (y0 > 0.f) ? y0 : expm1f(y0);
    y1 = (y1 > 0.f) ? y1 : expm1f(y1);
    y2 = (y2 > 0.f) ? y2 : expm1f(y2);
    y3 = (y3 > 0.f) ? y3 : expm1f(y3);
    const size_t rb = (size_t)e * (D + STAR);
    if (slot == 0) {
        *(float4*)(emsg + rb + sl * 4) = make_float4(y0, y1, y2, y3);
    } else {
        float2 s2 = *(const float2*)(S + (size_t)e * STAR + sl * 2);
        *(float2*)(emsg + rb + D + sl * 2) = s2;
    }
}

// ---------------------------------------------------------------------------
// K9: edge GEMM: Y = e_msg @ Wt^T + Wt_b -> fp16 (gather payload).
// M=20000, N=128, K=192.
// ---------------------------------------------------------------------------
#define BM 64
#define BN 64
#define BK 16

__global__ __launch_bounds__(256) void k_edge_gemm(
    const float* __restrict__ A, const float* __restrict__ Wt,
    const float* __restrict__ Wtb, __half* __restrict__ Y16)
{
    __shared__ float As[BK][BM + 4];
    __shared__ float Bs[BK][BN + 4];
    const int KDIM = D + STAR;   // 192
    const int tid = threadIdx.x;
    const int bm = blockIdx.x * BM;
    const int bn = blockIdx.y * BN;        // 0,64
    const int lr = tid >> 2;
    const int lk = (tid & 3) * 4;
    const int tx = tid & 15, ty = tid >> 4;

    float acc[4][4] = {};

    for (int k0 = 0; k0 < KDIM; k0 += BK) {
        float4 av = make_float4(0.f, 0.f, 0.f, 0.f);
        int row = bm + lr;
        if (row < N_EDGES)
            av = *(const float4*)(A + (size_t)row * KDIM + k0 + lk);
        As[lk + 0][lr] = av.x; As[lk + 1][lr] = av.y;
        As[lk + 2][lr] = av.z; As[lk + 3][lr] = av.w;
        int dd = bn + lr;   // < 128 always
        float4 bv = *(const float4*)(Wt + (size_t)dd * KDIM + k0 + lk);
        Bs[lk + 0][lr] = bv.x; Bs[lk + 1][lr] = bv.y;
        Bs[lk + 2][lr] = bv.z; Bs[lk + 3][lr] = bv.w;
        __syncthreads();
        #pragma unroll
        for (int kk = 0; kk < BK; ++kk) {
            float4 af = *(const float4*)&As[kk][ty * 4];
            float4 bf = *(const float4*)&Bs[kk][tx * 4];
            float a[4] = {af.x, af.y, af.z, af.w};
            float b[4] = {bf.x, bf.y, bf.z, bf.w};
            #pragma unroll
            for (int r = 0; r < 4; ++r)
                #pragma unroll
                for (int c = 0; c < 4; ++c)
                    acc[r][c] = fmaf(a[r], b[c], acc[r][c]);
        }
        __syncthreads();
    }

    const int gcol = bn + tx * 4;
    float4 bb = *(const float4*)(Wtb + gcol);
    #pragma unroll
    for (int r = 0; r < 4; ++r) {
        int row = bm + ty * 4 + r;
        if (row < N_EDGES) {
            __half2 h01 = __floats2half2_rn(acc[r][0] + bb.x, acc[r][1] + bb.y);
            __half2 h23 = __floats2half2_rn(acc[r][2] + bb.z, acc[r][3] + bb.w);
            *(__half2*)(Y16 + (size_t)row * D + gcol) = h01;
            *(__half2*)(Y16 + (size_t)row * D + gcol + 2) = h23;
        }
    }
}

// ---------------------------------------------------------------------------
// K10: per-node aggregation. ONE WAVE PER NODE, TWO 32-LANE SLOTS (as K8).
// out[v] = elu(mean_j Y[e_j]) + out[v]   (out holds X_init).
// ---------------------------------------------------------------------------
__global__ __launch_bounds__(256) void k_node_agg(
    const int* __restrict__ nedges, const int* __restrict__ noff,
    const __half* __restrict__ Y16, float* __restrict__ out)
{
    const int wave = threadIdx.x >> 6, lane = threadIdx.x & 63;
    const int v = blockIdx.x * 4 + wave;
    if (v >= N_NODES) return;
    const int beg = noff[v], end = noff[v + 1];
    const int slot = lane >> 5;
    const int sl = lane & 31;
    float a0 = 0.f, a1 = 0.f, a2 = 0.f, a3 = 0.f;
    int j = beg;
    #pragma unroll 2
    for (; j + 3 < end; j += 4) {
        int eA = nedges[j + slot];
        int eB = nedges[j + 2 + slot];
        float2 rA = *(const float2*)(Y16 + (size_t)eA * D + sl * 4);
        float2 rB = *(const float2*)(Y16 + (size_t)eB * D + sl * 4);
        acc4h(1.f, rA, a0, a1, a2, a3);
        acc4h(1.f, rB, a0, a1, a2, a3);
    }
    for (; j + 1 < end; j += 2) {
        int eA = nedges[j + slot];
        float2 rA = *(const float2*)(Y16 + (size_t)eA * D + sl * 4);
        acc4h(1.f, rA, a0, a1, a2, a3);
    }
    if (j < end && slot == 0) {
        int eA = nedges[j];
        float2 rA = *(const float2*)(Y16 + (size_t)eA * D + sl * 4);
        acc4h(1.f, rA, a0, a1, a2, a3);
    }
    a0 += __shfl_xor(a0, 32, 64);
    a1 += __shfl_xor(a1, 32, 64);
    a2 += __shfl_xor(a2, 32, 64);
    a3 += __shfl_xor(a3, 32, 64);

    int cnt = end - beg;
    float invc = 1.f / (float)max(cnt, 1);
    float x0 = a0 * invc, x1 = a1 * invc, x2 = a2 * invc, x3 = a3 * invc;
    x0 = (x0 > 0.f) ? x0 : expm1f(x0);
    x1 = (x1 > 0.f) ? x1 : expm1f(x1);
    x2 = (x2 > 0.f) ? x2 : expm1f(x2);
    x3 = (x3 > 0.f) ? x3 : expm1f(x3);
    if (slot == 0) {
        float4* o = (float4*)(out + (size_t)v * D + sl * 4);
        float4 cur = *o;
        *o = make_float4(cur.x + x0, cur.y + x1, cur.z + x2, cur.w + x3);
    }
}

// ---------------------------------------------------------------------------
extern "C" void kernel_launch(void* const* d_in, const int* in_sizes, int n_in,
                              void* d_out, int out_size, void* d_ws, size_t ws_size,
                              hipStream_t stream)
{
    const float* X    = (const float*)d_in[0];
    const int*   V    = (const int*)  d_in[1];
    const int*   E    = (const int*)  d_in[2];
    const float* S    = (const float*)d_in[3];
    const float* Wx_w = (const float*)d_in[4];
    const float* Wx_b = (const float*)d_in[5];
    const float* Wv_w = (const float*)d_in[6];
    const float* Wv_b = (const float*)d_in[7];
    const float* a_w  = (const float*)d_in[8];
    const float* Wt_w = (const float*)d_in[9];
    const float* Wt_b = (const float*)d_in[10];
    float* out = (float*)d_out;

    char* p = (char*)d_ws;
    auto take = [&](size_t bytes) -> char* {
        char* r = p;
        p += (bytes + 255) & ~(size_t)255;
        return r;
    };

    __half* Xf16  = (__half*)take((size_t)N_NODES * D * 2);
    float*  wexp  = (float*) take((size_t)N_NODES * 4);
    int*    part_e = (int*)  take((size_t)NBLK_E * N_EDGES * 4);
    int*    tot_e = (int*)   take((size_t)N_EDGES * 4);
    int*    nhist = (int*)   take((size_t)N_NODES * 4);
    int*    eoff  = (int*)   take((size_t)(N_EDGES + 1) * 4);
    int*    noff  = (int*)   take((size_t)(N_NODES + 1) * 4);
    int*    bsum_e = (int*)  take((size_t)SC_NBLK(N_EDGES) * 4);
    int*    bsum_n = (int*)  take((size_t)SC_NBLK(N_NODES) * 4);
    unsigned short* re = (unsigned short*)take((size_t)NNZ * 2);
    unsigned short* rn = (unsigned short*)take((size_t)NNZ * 2);
    int2*   epairs = (int2*) take((size_t)NNZ * 8);
    int*    nedges = (int*)  take((size_t)NNZ * 4);
    float*  emsg  = (float*) take((size_t)N_EDGES * (D + STAR) * 4);
    __half* Y16   = (__half*)take((size_t)N_EDGES * D * 2);

    hipMemsetAsync(nhist, 0, (size_t)N_NODES * 4, stream);

    k_node_gemm<<<(N_NODES + 63) / 64, 256, 0, stream>>>(
        X, Wx_w, Wx_b, Wv_w, Wv_b, out, Xf16);

    k_score<<<(N_NODES + 3) / 4, 256, 0, stream>>>(Xf16, a_w, wexp);

    k_part_e<<<dim3(NBLK_E, 2), 256, 0, stream>>>(E, part_e, re);

    k_rank_n<<<(NNZ + 255) / 256, 256, 0, stream>>>(V, nhist, rn);

    k_tot_e<<<(N_EDGES + 255) / 256, 256, 0, stream>>>(part_e, tot_e);

    // edge scan (n = 20000, 5 blocks)
    k_scan_bsum<<<SC_NBLK(N_EDGES), 256, 0, stream>>>(tot_e, bsum_e, N_EDGES);
    k_scan_bbase<<<1, 1024, 0, stream>>>(bsum_e, SC_NBLK(N_EDGES), eoff, N_EDGES);
    k_scan_out<<<SC_NBLK(N_EDGES), 256, 0, stream>>>(tot_e, bsum_e, eoff, N_EDGES);

    // node scan (n = 100000, 25 blocks)
    k_scan_bsum<<<SC_NBLK(N_NODES), 256, 0, stream>>>(nhist, bsum_n, N_NODES);
    k_scan_bbase<<<1, 1024, 0, stream>>>(bsum_n, SC_NBLK(N_NODES), noff, N_NODES);
    k_scan_out<<<SC_NBLK(N_NODES), 256, 0, stream>>>(nhist, bsum_n, noff, N_NODES);

    k_scatter_e<<<dim3(NBLK_E, 2), 256, 0, stream>>>(V, E, wexp, re, eoff,
                                                     part_e, epairs);
    k_scatter_n<<<(NNZ + 255) / 256, 256, 0, stream>>>(V, E, rn, noff, nedges);

    k_edge_agg<<<(N_EDGES + 3) / 4, 256, 0, stream>>>(epairs, eoff, Xf16, S, emsg);

    dim3 g6((N_EDGES + BM - 1) / BM, 2);
    k_edge_gemm<<<g6, 256, 0, stream>>>(emsg, Wt_w, Wt_b, Y16);

    k_node_agg<<<(N_NODES + 3) / 4, 256, 0, stream>>>(nedges, noff, Y16, out);
}

// Round 3
// 485.794 us; speedup vs baseline: 1.2599x; 1.0842x over previous
//
#include <hip/hip_runtime.h>
#include <hip/hip_bf16.h>
#include <hip/hip_fp16.h>

#define N_NODES 100000
#define N_EDGES 20000
#define NNZ     1600000
#define D       128
#define STAR    64
#define NEG_SLOPE 0.2f

// edge counting-sort partition
#define NBLK_E  200         // chunks
#define CHUNK_E 8000        // NNZ / NBLK_E
#define BINS_E  10000       // bins per LDS pass (40 KB int), 2 passes

// multi-block scan: 256 threads x 16 elements
#define SCC 16
#define SC_PER_BLOCK (256 * SCC)   // 4096
#define SC_NBLK(n) (((n) + SC_PER_BLOCK - 1) / SC_PER_BLOCK)

typedef _Float16 half8 __attribute__((ext_vector_type(8)));
typedef float    floatx4 __attribute__((ext_vector_type(4)));

// pack 8 fp32 (two float4) -> half8 fragment
__device__ __forceinline__ half8 cvt8(float4 f0, float4 f1)
{
    half8 h;
    h[0] = (_Float16)f0.x; h[1] = (_Float16)f0.y;
    h[2] = (_Float16)f0.z; h[3] = (_Float16)f0.w;
    h[4] = (_Float16)f1.x; h[5] = (_Float16)f1.y;
    h[6] = (_Float16)f1.z; h[7] = (_Float16)f1.w;
    return h;
}

// ---------------------------------------------------------------------------
// K0: one-time fp32 -> fp16 weight conversion.
// Wf16  = [Wx ; Wv]  (256 rows x 128)   = 64 KB
// Wtf16 = Wt         (128 rows x 192)   = 48 KB
// ---------------------------------------------------------------------------
__global__ __launch_bounds__(256) void k_cvt_w(
    const float* __restrict__ Wx, const float* __restrict__ Wv,
    const float* __restrict__ Wt,
    __half* __restrict__ Wf16, __half* __restrict__ Wtf16)
{
    int i = (blockIdx.x * 256 + threadIdx.x) * 4;
    const float* src;
    __half* dst;
    if (i < 16384)            { src = Wx + i;         dst = Wf16 + i; }
    else if (i < 32768)       { src = Wv + (i-16384); dst = Wf16 + i; }
    else if (i < 32768+24576) { src = Wt + (i-32768); dst = Wtf16 + (i-32768); }
    else return;
    float4 f = *(const float4*)src;
    *(__half2*)(dst)     = __floats2half2_rn(f.x, f.y);
    *(__half2*)(dst + 2) = __floats2half2_rn(f.z, f.w);
}

// ---------------------------------------------------------------------------
// K1: fused node GEMM on matrix cores, LDS-staged A, hoisted fp16 B.
//   [X_init | X_feat] = X @ [Wx^T | Wv^T] + bias
// Block = 64 rows x 256 cols, 4 waves (wave w -> cols 64w..64w+63).
// A: global fp32 -> cvt -> LDS fp16 [64][128], XOR-swizzled ((row&7)<<4)
//    to break the 256 B row-stride bank conflict (G4).
// B: 16 half8 fragments per wave hoisted from the 64 KB L2-resident Wf16.
// Main loop: 4 x {4 ds_read_b128 + 16 MFMA}; fp16 outputs repacked through
// LDS for fully-coalesced 16 B/lane stores.
// mfma_f32_16x16x32_f16 mapping (verified round 1): A row=lane&15,
// k=(lane>>4)*8+e; B col=lane&15 same k; C/D col=lane&15, row=(lane>>4)*4+q.
// ---------------------------------------------------------------------------
__global__ __launch_bounds__(256) void k_node_gemm(
    const float* __restrict__ X, const __half* __restrict__ Wf16,
    const float* __restrict__ Wxb, const float* __restrict__ Wvb,
    float* __restrict__ Xinit, __half* __restrict__ Xf16)
{
    __shared__ char smem[64 * 256];   // 16 KB A-tile; reused for fp16 repack
    const int tid  = threadIdx.x;
    const int w    = tid >> 6;
    const int lane = tid & 63;
    const int bm   = blockIdx.x * 64;
    const int colbase = w * 64;               // 0,64,128,192
    const bool isInit = (colbase < D);
    const int r16 = lane & 15;
    const int hi  = lane >> 4;                // 0..3
    const int g8  = hi * 8;

    // ---- stage A tile: coalesced fp32 load -> fp16 -> swizzled LDS ----
    {
        const int r  = tid >> 2;              // 0..63
        int srow = bm + r; if (srow >= N_NODES) srow = N_NODES - 1;
        const float4* src = (const float4*)(X + (size_t)srow * D + (tid & 3) * 32);
        float4 f[8];
        #pragma unroll
        for (int j = 0; j < 8; ++j) f[j] = src[j];
        const int swz  = (r & 7) << 4;
        const int base = r * 256 + (tid & 3) * 64;
        #pragma unroll
        for (int j = 0; j < 4; ++j)
            *(half8*)(smem + ((base + j * 16) ^ swz)) = cvt8(f[2*j], f[2*j+1]);
    }

    // ---- hoist all 16 B fragments (fp16, L2-resident) ----
    half8 bf[4][4];
    #pragma unroll
    for (int ks = 0; ks < 4; ++ks)
        #pragma unroll
        for (int n = 0; n < 4; ++n)
            bf[ks][n] = *(const half8*)(Wf16 + (size_t)(colbase + n*16 + r16) * D
                                        + ks * 32 + g8);

    __syncthreads();

    floatx4 acc[4][4] = {};
    #pragma unroll
    for (int ks = 0; ks < 4; ++ks) {
        half8 a[4];
        #pragma unroll
        for (int m = 0; m < 4; ++m) {
            const int R = m * 16 + r16;
            a[m] = *(const half8*)(smem + ((R*256 + ks*64 + hi*16) ^ ((R&7)<<4)));
        }
        #pragma unroll
        for (int m = 0; m < 4; ++m)
            #pragma unroll
            for (int n = 0; n < 4; ++n)
                acc[m][n] = __builtin_amdgcn_mfma_f32_16x16x32_f16(
                    a[m], bf[ks][n], acc[m][n], 0, 0, 0);
    }

    const float* bias = isInit ? Wxb : Wvb;
    const int rq = hi * 4;

    __syncthreads();   // A-tile dead; smem reusable

    if (isInit) {
        // fp32 stores: 16-lane groups write aligned 64 B segments
        #pragma unroll
        for (int n = 0; n < 4; ++n) {
            const int c = (colbase & (D - 1)) + n * 16 + r16;
            const float bv = bias[c];
            #pragma unroll
            for (int m = 0; m < 4; ++m)
                #pragma unroll
                for (int q = 0; q < 4; ++q) {
                    const int row = bm + m * 16 + rq + q;
                    if (row < N_NODES)
                        Xinit[(size_t)row * D + c] = acc[m][n][q] + bv;
                }
        }
    } else {
        // scatter fp16 values into LDS tile [64 rows][128 halves]
        __half* sh = (__half*)smem;
        #pragma unroll
        for (int n = 0; n < 4; ++n) {
            const int lc = (colbase - D) + n * 16 + r16;   // 0..127
            const float bv = bias[(colbase & (D - 1)) + n * 16 + r16];
            #pragma unroll
            for (int m = 0; m < 4; ++m)
                #pragma unroll
                for (int q = 0; q < 4; ++q)
                    sh[(m * 16 + rq + q) * 128 + lc] =
                        __float2half(acc[m][n][q] + bv);
        }
    }
    __syncthreads();
    // cooperative fully-coalesced Xf16 store: 64 rows x 256 B contiguous
    {
        const int r   = tid >> 2;
        const int row = bm + r;
        if (row < N_NODES) {
            const char* src = smem + r * 256 + (tid & 3) * 64;
            __half* dst = Xf16 + (size_t)row * D + (tid & 3) * 32;
            #pragma unroll
            for (int j = 0; j < 4; ++j)
                *(half8*)(dst + j * 8) = *(const half8*)(src + j * 16);
        }
    }
}

// ---------------------------------------------------------------------------
// K2: wexp[n] = exp(leaky_relu(X_feat[n,:] . a_w)) — one wave per node.
// ---------------------------------------------------------------------------
__global__ __launch_bounds__(256) void k_score(
    const __half* __restrict__ Xf16, const float* __restrict__ aw,
    float* __restrict__ wexp)
{
    const int wave = threadIdx.x >> 6, lane = threadIdx.x & 63;
    const int node = blockIdx.x * 4 + wave;
    if (node >= N_NODES) return;
    __half2 h = *(const __half2*)(Xf16 + (size_t)node * D + lane * 2);
    float2 x = __half22float2(h);
    float2 a = *(const float2*)(aw + lane * 2);
    float s = x.x * a.x + x.y * a.y;
    #pragma unroll
    for (int off = 32; off > 0; off >>= 1) s += __shfl_down(s, off, 64);
    if (lane == 0) {
        float l = (s > 0.f) ? s : NEG_SLOPE * s;
        wexp[node] = expf(l);
    }
}

// ---------------------------------------------------------------------------
// K3: edge histogram + within-(block,bin) rank via LDS atomics ONLY.
// ---------------------------------------------------------------------------
__global__ __launch_bounds__(256) void k_part_e(
    const int* __restrict__ E, int* __restrict__ part,
    unsigned short* __restrict__ re)
{
    __shared__ int h[BINS_E];
    const int b = blockIdx.x;
    const int c0 = blockIdx.y * BINS_E;
    const int i0 = b * CHUNK_E;
    for (int t = threadIdx.x; t < BINS_E; t += 256) h[t] = 0;
    __syncthreads();
    for (int i = threadIdx.x; i < CHUNK_E; i += 256) {
        int c = E[i0 + i] - c0;
        if (c >= 0 && c < BINS_E) {
            int r = atomicAdd(&h[c], 1);            // LDS atomic, returns rank
            re[i0 + i] = (unsigned short)r;
        }
    }
    __syncthreads();
    for (int t = threadIdx.x; t < BINS_E; t += 256)
        part[(size_t)b * N_EDGES + c0 + t] = h[t];
}

// ---------------------------------------------------------------------------
// K4: node rank via ONE global atomic per incidence (returns rank).
// ---------------------------------------------------------------------------
__global__ __launch_bounds__(256) void k_rank_n(
    const int* __restrict__ V, int* __restrict__ nhist,
    unsigned short* __restrict__ rn)
{
    int i = blockIdx.x * 256 + threadIdx.x;
    if (i >= NNZ) return;
    int r = atomicAdd(nhist + V[i], 1);             // device atomic (rank)
    rn[i] = (unsigned short)r;
}

// ---------------------------------------------------------------------------
// K5: per-bin exclusive prefix over edge chunks; emits per-bin totals.
// ---------------------------------------------------------------------------
__global__ __launch_bounds__(256) void k_tot_e(
    int* __restrict__ part, int* __restrict__ tot)
{
    int bin = blockIdx.x * 256 + threadIdx.x;
    if (bin >= N_EDGES) return;
    int run = 0;
    for (int b = 0; b < NBLK_E; ++b) {
        size_t idx = (size_t)b * N_EDGES + bin;
        int v = part[idx];
        part[idx] = run;
        run += v;
    }
    tot[bin] = run;
}

// ---------------------------------------------------------------------------
// Multi-block scan, phase 1: per-block sums. 256 thr x 16 elems (int4).
// ---------------------------------------------------------------------------
__global__ __launch_bounds__(256) void k_scan_bsum(
    const int* __restrict__ cnt, int* __restrict__ bsum, int n)
{
    __shared__ int red[256];
    const int base = blockIdx.x * SC_PER_BLOCK + threadIdx.x * SCC;
    int s = 0;
    if (base + SCC <= n) {
        const int4* p4 = (const int4*)(cnt + base);
        #pragma unroll
        for (int j = 0; j < SCC / 4; ++j) {
            int4 v = p4[j];
            s += v.x + v.y + v.z + v.w;
        }
    } else {
        for (int i = base; i < n; ++i) s += cnt[i];
    }
    red[threadIdx.x] = s;
    __syncthreads();
    for (int d = 128; d > 0; d >>= 1) {
        if (threadIdx.x < d) red[threadIdx.x] += red[threadIdx.x + d];
        __syncthreads();
    }
    if (threadIdx.x == 0) bsum[blockIdx.x] = red[0];
}

// ---------------------------------------------------------------------------
// Phase 2: single small block turns bsum into exclusive block bases,
// writes total into off[n].  nb <= 1024.
// ---------------------------------------------------------------------------
__global__ __launch_bounds__(1024) void k_scan_bbase(
    int* __restrict__ bsum, int nb, int* __restrict__ off, int n)
{
    __shared__ int sums[1024];
    const int tid = threadIdx.x;
    sums[tid] = (tid < nb) ? bsum[tid] : 0;
    __syncthreads();
    for (int d = 1; d < 1024; d <<= 1) {
        int mine = sums[tid];
        int other = (tid >= d) ? sums[tid - d] : 0;
        __syncthreads();
        sums[tid] = mine + other;
        __syncthreads();
    }
    if (tid < nb) bsum[tid] = (tid > 0) ? sums[tid - 1] : 0;
    if (tid == 0) off[n] = sums[1023];
}

// ---------------------------------------------------------------------------
// Phase 3: per-block exclusive scan + block base -> off[i].
// ---------------------------------------------------------------------------
__global__ __launch_bounds__(256) void k_scan_out(
    const int* __restrict__ cnt, const int* __restrict__ bsum,
    int* __restrict__ off, int n)
{
    __shared__ int tsum[256];
    const int base = blockIdx.x * SC_PER_BLOCK + threadIdx.x * SCC;
    int vals[SCC];
    int s = 0;
    if (base + SCC <= n) {
        const int4* p4 = (const int4*)(cnt + base);
        #pragma unroll
        for (int j = 0; j < SCC / 4; ++j) {
            int4 v = p4[j];
            vals[4 * j + 0] = v.x; vals[4 * j + 1] = v.y;
            vals[4 * j + 2] = v.z; vals[4 * j + 3] = v.w;
            s += v.x + v.y + v.z + v.w;
        }
    } else {
        #pragma unroll
        for (int j = 0; j < SCC; ++j) {
            int i = base + j;
            vals[j] = (i < n) ? cnt[i] : 0;
            s += vals[j];
        }
    }
    tsum[threadIdx.x] = s;
    __syncthreads();
    for (int d = 1; d < 256; d <<= 1) {
        int mine = tsum[threadIdx.x];
        int other = (threadIdx.x >= d) ? tsum[threadIdx.x - d] : 0;
        __syncthreads();
        tsum[threadIdx.x] = mine + other;
        __syncthreads();
    }
    int run = bsum[blockIdx.x] + ((threadIdx.x > 0) ? tsum[threadIdx.x - 1] : 0);
    #pragma unroll
    for (int j = 0; j < SCC; ++j) {
        int i = base + j;
        if (i < n) { off[i] = run; run += vals[j]; }
    }
}

// ---------------------------------------------------------------------------
// K6: edge scatter, NO atomics. w gathered from 400 KB wexp table.
// ---------------------------------------------------------------------------
__global__ __launch_bounds__(256) void k_scatter_e(
    const int* __restrict__ V, const int* __restrict__ E,
    const float* __restrict__ wexp, const unsigned short* __restrict__ re,
    const int* __restrict__ eoff, const int* __restrict__ part,
    int2* __restrict__ epairs)
{
    __shared__ int base[BINS_E];
    const int b = blockIdx.x;
    const int c0 = blockIdx.y * BINS_E;
    const int i0 = b * CHUNK_E;
    for (int t = threadIdx.x; t < BINS_E; t += 256)
        base[t] = part[(size_t)b * N_EDGES + c0 + t] + eoff[c0 + t];
    __syncthreads();
    for (int i = threadIdx.x; i < CHUNK_E; i += 256) {
        int e = E[i0 + i];
        int c = e - c0;
        if (c >= 0 && c < BINS_E) {
            int v = V[i0 + i];
            float w = wexp[v];
            epairs[base[c] + re[i0 + i]] = make_int2(v, __float_as_int(w));
        }
    }
}

// ---------------------------------------------------------------------------
// K7: node scatter, NO atomics, flat grid: pos = noff[V[i]] + rn[i].
// ---------------------------------------------------------------------------
__global__ __launch_bounds__(256) void k_scatter_n(
    const int* __restrict__ V, const int* __restrict__ E,
    const unsigned short* __restrict__ rn, const int* __restrict__ noff,
    int* __restrict__ nedges)
{
    int i = blockIdx.x * 256 + threadIdx.x;
    if (i >= NNZ) return;
    nedges[noff[V[i]] + rn[i]] = E[i];
}

// ---------------------------------------------------------------------------
// helper: accumulate 4 dims (stored as 4 halves in a float2) with weight w
// ---------------------------------------------------------------------------
__device__ __forceinline__ void acc4h(float w, float2 raw,
                                      float& a0, float& a1,
                                      float& a2, float& a3)
{
    __half2 h01 = *(__half2*)&raw.x;
    __half2 h23 = *(__half2*)&raw.y;
    float2 f01 = __half22float2(h01);
    float2 f23 = __half22float2(h23);
    a0 = fmaf(w, f01.x, a0); a1 = fmaf(w, f01.y, a1);
    a2 = fmaf(w, f23.x, a2); a3 = fmaf(w, f23.y, a3);
}

// ---------------------------------------------------------------------------
// K8: per-edge aggregation. ONE WAVE PER EDGE, TWO 32-LANE SLOTS.
// ---------------------------------------------------------------------------
__global__ __launch_bounds__(256) void k_edge_agg(
    const int2* __restrict__ epairs, const int* __restrict__ eoff,
    const __half* __restrict__ Xf16, const float* __restrict__ S,
    float* __restrict__ emsg)
{
    const int wave = threadIdx.x >> 6, lane = threadIdx.x & 63;
    const int e = blockIdx.x * 4 + wave;
    if (e >= N_EDGES) return;
    const int beg = eoff[e], end = eoff[e + 1];
    const int slot = lane >> 5;          // 0 or 1
    const int sl = lane & 31;            // lane within slot: dims 4*sl..4*sl+3
    float a0 = 0.f, a1 = 0.f, a2 = 0.f, a3 = 0.f, dsum = 0.f;
    int j = beg;
    #pragma unroll 2
    for (; j + 3 < end; j += 4) {
        int2 pA = epairs[j + slot];
        int2 pB = epairs[j + 2 + slot];
        float wA = __int_as_float(pA.y), wB = __int_as_float(pB.y);
        float2 rA = *(const float2*)(Xf16 + (size_t)pA.x * D + sl * 4);
        float2 rB = *(const float2*)(Xf16 + (size_t)pB.x * D + sl * 4);
        dsum += wA + wB;
        acc4h(wA, rA, a0, a1, a2, a3);
        acc4h(wB, rB, a0, a1, a2, a3);
    }
    for (; j + 1 < end; j += 2) {
        int2 p = epairs[j + slot];
        float w = __int_as_float(p.y);
        float2 r = *(const float2*)(Xf16 + (size_t)p.x * D + sl * 4);
        dsum += w;
        acc4h(w, r, a0, a1, a2, a3);
    }
    if (j < end && slot == 0) {
        int2 p = epairs[j];
        float w = __int_as_float(p.y);
        float2 r = *(const float2*)(Xf16 + (size_t)p.x * D + sl * 4);
        dsum += w;
        acc4h(w, r, a0, a1, a2, a3);
    }
    a0 += __shfl_xor(a0, 32, 64);
    a1 += __shfl_xor(a1, 32, 64);
    a2 += __shfl_xor(a2, 32, 64);
    a3 += __shfl_xor(a3, 32, 64);
    dsum += __shfl_xor(dsum, 32, 64);

    float inv = (end > beg) ? 1.f / dsum : 0.f;
    float y0 = a0 * inv, y1 = a1 * inv, y2 = a2 * inv, y3 = a3 * inv;
    y0 = (y0 > 0.f) ? y0 : expm1f(y0);
    y1 = (y1 > 0.f) ? y1 : expm1f(y1);
    y2 = (y2 > 0.f) ? y2 : expm1f(y2);
    y3 = (y3 > 0.f) ? y3 : expm1f(y3);
    const size_t rb = (size_t)e * (D + STAR);
    if (slot == 0) {
        *(float4*)(emsg + rb + sl * 4) = make_float4(y0, y1, y2, y3);
    } else {
        float2 s2 = *(const float2*)(S + (size_t)e * STAR + sl * 2);
        *(float2*)(emsg + rb + D + sl * 2) = s2;
    }
}

// ---------------------------------------------------------------------------
// K9: edge GEMM on matrix cores: Y = e_msg @ Wt^T + Wt_b -> fp16.
// M=20000, N=128, K=192. Same structure as K1: LDS-staged fp16 A
// (row stride 384 B, same XOR swizzle), hoisted fp16 B (12 frags),
// 6 x {4 ds_read + 8 MFMA}, LDS-repacked coalesced fp16 store.
// Block = 64 rows x 128 cols, 4 waves (wave w -> cols 32w..32w+31).
// ---------------------------------------------------------------------------
__global__ __launch_bounds__(256) void k_edge_gemm(
    const float* __restrict__ A, const __half* __restrict__ Wtf16,
    const float* __restrict__ Wtb, __half* __restrict__ Y16)
{
    __shared__ char smem[64 * 384];   // 24 KB A-tile; head reused for repack
    const int KDIM = D + STAR;        // 192
    const int tid  = threadIdx.x;
    const int w    = tid >> 6;
    const int lane = tid & 63;
    const int bm   = blockIdx.x * 64;
    const int colbase = w * 32;       // 0,32,64,96
    const int r16 = lane & 15;
    const int hi  = lane >> 4;
    const int g8  = hi * 8;

    // ---- stage A tile: 4 threads/row, 48 floats each (contiguous 768 B/row)
    {
        const int r = tid >> 2;
        int srow = bm + r; if (srow >= N_EDGES) srow = N_EDGES - 1;
        const float4* src = (const float4*)(A + (size_t)srow * KDIM + (tid & 3) * 48);
        float4 f[12];
        #pragma unroll
        for (int j = 0; j < 12; ++j) f[j] = src[j];
        const int swz  = (r & 7) << 4;
        const int base = r * 384 + (tid & 3) * 96;
        #pragma unroll
        for (int j = 0; j < 6; ++j)
            *(half8*)(smem + ((base + j * 16) ^ swz)) = cvt8(f[2*j], f[2*j+1]);
    }

    // ---- hoist 12 B fragments ----
    half8 bf[6][2];
    #pragma unroll
    for (int ks = 0; ks < 6; ++ks)
        #pragma unroll
        for (int n = 0; n < 2; ++n)
            bf[ks][n] = *(const half8*)(Wtf16 + (size_t)(colbase + n*16 + r16) * KDIM
                                        + ks * 32 + g8);

    __syncthreads();

    floatx4 acc[4][2] = {};
    #pragma unroll
    for (int ks = 0; ks < 6; ++ks) {
        half8 a[4];
        #pragma unroll
        for (int m = 0; m < 4; ++m) {
            const int R = m * 16 + r16;
            a[m] = *(const half8*)(smem + ((R*384 + ks*64 + hi*16) ^ ((R&7)<<4)));
        }
        #pragma unroll
        for (int m = 0; m < 4; ++m)
            #pragma unroll
            for (int n = 0; n < 2; ++n)
                acc[m][n] = __builtin_amdgcn_mfma_f32_16x16x32_f16(
                    a[m], bf[ks][n], acc[m][n], 0, 0, 0);
    }

    const int rq = hi * 4;
    __syncthreads();   // A-tile dead

    // scatter fp16 results into LDS tile [64 rows][128 halves]
    {
        __half* sh = (__half*)smem;
        #pragma unroll
        for (int n = 0; n < 2; ++n) {
            const int c = colbase + n * 16 + r16;     // 0..127
            const float bv = Wtb[c];
            #pragma unroll
            for (int m = 0; m < 4; ++m)
                #pragma unroll
                for (int q = 0; q < 4; ++q)
                    sh[(m * 16 + rq + q) * 128 + c] =
                        __float2half(acc[m][n][q] + bv);
        }
    }
    __syncthreads();
    // coalesced store: 64 rows x 256 B contiguous
    {
        const int r   = tid >> 2;
        const int row = bm + r;
        if (row < N_EDGES) {
            const char* src = smem + r * 256 + (tid & 3) * 64;
            __half* dst = Y16 + (size_t)row * D + (tid & 3) * 32;
            #pragma unroll
            for (int j = 0; j < 4; ++j)
                *(half8*)(dst + j * 8) = *(const half8*)(src + j * 16);
        }
    }
}

// ---------------------------------------------------------------------------
// K10: per-node aggregation. ONE WAVE PER NODE, TWO 32-LANE SLOTS (as K8).
// out[v] = elu(mean_j Y[e_j]) + out[v]   (out holds X_init).
// ---------------------------------------------------------------------------
__global__ __launch_bounds__(256) void k_node_agg(
    const int* __restrict__ nedges, const int* __restrict__ noff,
    const __half* __restrict__ Y16, float* __restrict__ out)
{
    const int wave = threadIdx.x >> 6, lane = threadIdx.x & 63;
    const int v = blockIdx.x * 4 + wave;
    if (v >= N_NODES) return;
    const int beg = noff[v], end = noff[v + 1];
    const int slot = lane >> 5;
    const int sl = lane & 31;
    float a0 = 0.f, a1 = 0.f, a2 = 0.f, a3 = 0.f;
    int j = beg;
    #pragma unroll 2
    for (; j + 3 < end; j += 4) {
        int eA = nedges[j + slot];
        int eB = nedges[j + 2 + slot];
        float2 rA = *(const float2*)(Y16 + (size_t)eA * D + sl * 4);
        float2 rB = *(const float2*)(Y16 + (size_t)eB * D + sl * 4);
        acc4h(1.f, rA, a0, a1, a2, a3);
        acc4h(1.f, rB, a0, a1, a2, a3);
    }
    for (; j + 1 < end; j += 2) {
        int eA = nedges[j + slot];
        float2 rA = *(const float2*)(Y16 + (size_t)eA * D + sl * 4);
        acc4h(1.f, rA, a0, a1, a2, a3);
    }
    if (j < end && slot == 0) {
        int eA = nedges[j];
        float2 rA = *(const float2*)(Y16 + (size_t)eA * D + sl * 4);
        acc4h(1.f, rA, a0, a1, a2, a3);
    }
    a0 += __shfl_xor(a0, 32, 64);
    a1 += __shfl_xor(a1, 32, 64);
    a2 += __shfl_xor(a2, 32, 64);
    a3 += __shfl_xor(a3, 32, 64);

    int cnt = end - beg;
    float invc = 1.f / (float)max(cnt, 1);
    float x0 = a0 * invc, x1 = a1 * invc, x2 = a2 * invc, x3 = a3 * invc;
    x0 = (x0 > 0.f) ? x0 : expm1f(x0);
    x1 = (x1 > 0.f) ? x1 : expm1f(x1);
    x2 = (x2 > 0.f) ? x2 : expm1f(x2);
    x3 = (x3 > 0.f) ? x3 : expm1f(x3);
    if (slot == 0) {
        float4* o = (float4*)(out + (size_t)v * D + sl * 4);
        float4 cur = *o;
        *o = make_float4(cur.x + x0, cur.y + x1, cur.z + x2, cur.w + x3);
    }
}

// ---------------------------------------------------------------------------
extern "C" void kernel_launch(void* const* d_in, const int* in_sizes, int n_in,
                              void* d_out, int out_size, void* d_ws, size_t ws_size,
                              hipStream_t stream)
{
    const float* X    = (const float*)d_in[0];
    const int*   V    = (const int*)  d_in[1];
    const int*   E    = (const int*)  d_in[2];
    const float* S    = (const float*)d_in[3];
    const float* Wx_w = (const float*)d_in[4];
    const float* Wx_b = (const float*)d_in[5];
    const float* Wv_w = (const float*)d_in[6];
    const float* Wv_b = (const float*)d_in[7];
    const float* a_w  = (const float*)d_in[8];
    const float* Wt_w = (const float*)d_in[9];
    const float* Wt_b = (const float*)d_in[10];
    float* out = (float*)d_out;

    char* p = (char*)d_ws;
    auto take = [&](size_t bytes) -> char* {
        char* r = p;
        p += (bytes + 255) & ~(size_t)255;
        return r;
    };

    __half* Xf16  = (__half*)take((size_t)N_NODES * D * 2);
    float*  wexp  = (float*) take((size_t)N_NODES * 4);
    int*    part_e = (int*)  take((size_t)NBLK_E * N_EDGES * 4);
    int*    tot_e = (int*)   take((size_t)N_EDGES * 4);
    int*    nhist = (int*)   take((size_t)N_NODES * 4);
    int*    eoff  = (int*)   take((size_t)(N_EDGES + 1) * 4);
    int*    noff  = (int*)   take((size_t)(N_NODES + 1) * 4);
    int*    bsum_e = (int*)  take((size_t)SC_NBLK(N_EDGES) * 4);
    int*    bsum_n = (int*)  take((size_t)SC_NBLK(N_NODES) * 4);
    unsigned short* re = (unsigned short*)take((size_t)NNZ * 2);
    unsigned short* rn = (unsigned short*)take((size_t)NNZ * 2);
    int2*   epairs = (int2*) take((size_t)NNZ * 8);
    int*    nedges = (int*)  take((size_t)NNZ * 4);
    float*  emsg  = (float*) take((size_t)N_EDGES * (D + STAR) * 4);
    __half* Y16   = (__half*)take((size_t)N_EDGES * D * 2);
    __half* Wf16  = (__half*)take((size_t)256 * D * 2);          // [Wx;Wv] fp16
    __half* Wtf16 = (__half*)take((size_t)D * (D + STAR) * 2);   // Wt fp16

    hipMemsetAsync(nhist, 0, (size_t)N_NODES * 4, stream);

    k_cvt_w<<<56, 256, 0, stream>>>(Wx_w, Wv_w, Wt_w, Wf16, Wtf16);

    k_node_gemm<<<(N_NODES + 63) / 64, 256, 0, stream>>>(
        X, Wf16, Wx_b, Wv_b, out, Xf16);

    k_score<<<(N_NODES + 3) / 4, 256, 0, stream>>>(Xf16, a_w, wexp);

    k_part_e<<<dim3(NBLK_E, 2), 256, 0, stream>>>(E, part_e, re);

    k_rank_n<<<(NNZ + 255) / 256, 256, 0, stream>>>(V, nhist, rn);

    k_tot_e<<<(N_EDGES + 255) / 256, 256, 0, stream>>>(part_e, tot_e);

    // edge scan (n = 20000, 5 blocks)
    k_scan_bsum<<<SC_NBLK(N_EDGES), 256, 0, stream>>>(tot_e, bsum_e, N_EDGES);
    k_scan_bbase<<<1, 1024, 0, stream>>>(bsum_e, SC_NBLK(N_EDGES), eoff, N_EDGES);
    k_scan_out<<<SC_NBLK(N_EDGES), 256, 0, stream>>>(tot_e, bsum_e, eoff, N_EDGES);

    // node scan (n = 100000, 25 blocks)
    k_scan_bsum<<<SC_NBLK(N_NODES), 256, 0, stream>>>(nhist, bsum_n, N_NODES);
    k_scan_bbase<<<1, 1024, 0, stream>>>(bsum_n, SC_NBLK(N_NODES), noff, N_NODES);
    k_scan_out<<<SC_NBLK(N_NODES), 256, 0, stream>>>(nhist, bsum_n, noff, N_NODES);

    k_scatter_e<<<dim3(NBLK_E, 2), 256, 0, stream>>>(V, E, wexp, re, eoff,
                                                     part_e, epairs);
    k_scatter_n<<<(NNZ + 255) / 256, 256, 0, stream>>>(V, E, rn, noff, nedges);

    k_edge_agg<<<(N_EDGES + 3) / 4, 256, 0, stream>>>(epairs, eoff, Xf16, S, emsg);

    k_edge_gemm<<<(N_EDGES + 63) / 64, 256, 0, stream>>>(emsg, Wtf16, Wt_b, Y16);

    k_node_agg<<<(N_NODES + 3) / 4, 256, 0, stream>>>(nedges, noff, Y16, out);
}